// Round 1
// baseline (125.653 us; speedup 1.0000x reference)
//
#include <hip/hip_runtime.h>
#include <hip/hip_bf16.h>

#define BB 8
#define CIN 256
#define COUT 128
#define HIN 128
#define WIN 128
#define HOUT 256
#define WOUT 256

typedef __attribute__((ext_vector_type(8))) short bf16x8;
typedef __attribute__((ext_vector_type(4))) float f32x4;

__device__ __forceinline__ short f2bf(float f) {
  __hip_bfloat16 h = __float2bfloat16(f);  // RNE; compiler can fuse pairs to v_cvt_pk_bf16_f32
  return *reinterpret_cast<short*>(&h);
}

// ---------------- Kernel 0: W fp32 -> bf16 (row-major [COUT][CIN]) --------
__global__ __launch_bounds__(256) void wconv_kernel(const float* __restrict__ wgt,
                                                    short* __restrict__ wbf) {
  int idx = (blockIdx.x * 256 + threadIdx.x) * 4;
  float4 f = *reinterpret_cast<const float4*>(wgt + idx);
  short4 pk = make_short4(f2bf(f.x), f2bf(f.y), f2bf(f.z), f2bf(f.w));
  *reinterpret_cast<short4*>(wbf + idx) = pk;
}

// ---------------- Kernel 1: z[b][o][h][w] = sum_c W[o][c] x[b][c][h][w] ----
// grid (128 h, 8 b), 256 threads (4 waves, 2x2 wave tile over M=128(o) x N=128(w))
__global__ __launch_bounds__(256) void conv1x1_kernel(const float* __restrict__ x,
                                                      const short* __restrict__ wbf,
                                                      float* __restrict__ z) {
  // xs[p][c] bf16, +8 pad (16B) -> rows 528B: 16B-aligned fragments, spread banks
  __shared__ __align__(16) short xs[128][264];
  const int h = blockIdx.x, b = blockIdx.y;
  const int t = threadIdx.x;

  // stage x[b][:, h, :] transposed to [w][c], converting to bf16.
  // thread: fixed w = t&127, c-half = t>>7; loads 4 consecutive-c scalars
  // (each load coalesced across the 64 w-lanes), packs to 8B ds_write.
  {
    const float* xb = x + (size_t)b * (CIN * HIN * WIN) + (size_t)h * WIN;
    int w0 = t & 127;
    int ch = t >> 7;
#pragma unroll
    for (int cc = 0; cc < 32; ++cc) {
      int c = ch * 128 + cc * 4;
      float f0 = xb[(size_t)(c + 0) * (HIN * WIN) + w0];
      float f1 = xb[(size_t)(c + 1) * (HIN * WIN) + w0];
      float f2 = xb[(size_t)(c + 2) * (HIN * WIN) + w0];
      float f3 = xb[(size_t)(c + 3) * (HIN * WIN) + w0];
      short4 pk = make_short4(f2bf(f0), f2bf(f1), f2bf(f2), f2bf(f3));
      *reinterpret_cast<short4*>(&xs[w0][c]) = pk;
    }
  }
  __syncthreads();

  const int lane = t & 63, wid = t >> 6;
  const int wm = wid >> 1, wn = wid & 1;  // wave owns 64(o) x 64(w)
  const int r = lane & 15, g = lane >> 4;

  f32x4 acc[4][4];
#pragma unroll
  for (int i = 0; i < 4; ++i)
#pragma unroll
    for (int j = 0; j < 4; ++j)
      acc[i][j] = (f32x4){0.f, 0.f, 0.f, 0.f};

#pragma unroll
  for (int ks = 0; ks < 8; ++ks) {
    int cb = ks * 32 + g * 8;
    bf16x8 afr[4], bfr[4];
#pragma unroll
    for (int mt = 0; mt < 4; ++mt) {
      int o = wm * 64 + mt * 16 + r;
      afr[mt] = *reinterpret_cast<const bf16x8*>(wbf + (size_t)o * CIN + cb);
    }
#pragma unroll
    for (int nt = 0; nt < 4; ++nt) {
      int p = wn * 64 + nt * 16 + r;
      bfr[nt] = *reinterpret_cast<const bf16x8*>(&xs[p][cb]);
    }
#pragma unroll
    for (int mt = 0; mt < 4; ++mt)
#pragma unroll
      for (int nt = 0; nt < 4; ++nt)
        acc[mt][nt] = __builtin_amdgcn_mfma_f32_16x16x32_bf16(afr[mt], bfr[nt], acc[mt][nt], 0, 0, 0);
  }

  // C/D layout: col = lane&15 (w), row = (lane>>4)*4 + q (o)
  float* zb = z + (size_t)b * (COUT * HIN * WIN) + (size_t)h * WIN;
#pragma unroll
  for (int mt = 0; mt < 4; ++mt) {
#pragma unroll
    for (int nt = 0; nt < 4; ++nt) {
      int p = wn * 64 + nt * 16 + r;
      int ob = wm * 64 + mt * 16 + g * 4;
#pragma unroll
      for (int q = 0; q < 4; ++q)
        zb[(size_t)(ob + q) * (HIN * WIN) + p] = acc[mt][nt][q];
    }
  }
}

// ---------------- Kernel 2: separable bicubic 2x + bias + LeakyReLU -------
#define ACF (-0.75f)
#define SC (127.0f / 255.0f)
#define NEG 0.01f

__device__ __forceinline__ float cub_le1(float s) {  // 0 <= s <= 1
  return ((ACF + 2.0f) * s - (ACF + 3.0f)) * s * s + 1.0f;
}
__device__ __forceinline__ float cub_gt1(float s) {  // 1 < s <= 2 (==0 at s=1,2)
  return (((s - 5.0f) * s + 8.0f) * s - 4.0f) * ACF;
}

// grid.x = 1024 (o = bx>>3, itile = bx&7), grid.y = b; 256 threads
__global__ __launch_bounds__(256) void upsample_kernel(const float* __restrict__ z,
                                                       const float* __restrict__ bias,
                                                       float* __restrict__ out) {
  __shared__ float4 wwj[256];
  __shared__ int4 jidx[256];
  __shared__ float4 whv[32];
  __shared__ int4 hrr[32];
  __shared__ float zrow[20][128];
  __shared__ float trow[20][256];

  const int bx = blockIdx.x;
  const int itile = bx & 7;
  const int o = bx >> 3;
  const int b = blockIdx.y;
  const int t = threadIdx.x;

  // uniform h-range for this 32-row output tile
  const int i_first = itile * 32, i_last = i_first + 31;
  const int h0f = (int)floorf(i_first * SC);
  const int h0l = (int)floorf(i_last * SC);
  const int hmin = max(h0f - 1, 0);
  const int hmax = min(h0l + 2, HIN - 1);
  const int nh = hmax - hmin + 1;  // <= 20

  // horizontal weights (one j per thread)
  {
    int j = t;
    float src = j * SC;
    float fj = floorf(src);
    int j0 = (int)fj;
    float tt = src - fj;
    wwj[j] = make_float4(cub_gt1(1.0f + tt), cub_le1(tt), cub_le1(1.0f - tt), cub_gt1(2.0f - tt));
    jidx[j] = make_int4(min(max(j0 - 1, 0), WIN - 1), min(max(j0, 0), WIN - 1),
                        min(max(j0 + 1, 0), WIN - 1), min(max(j0 + 2, 0), WIN - 1));
  }
  // vertical weights for this tile's 32 rows
  if (t < 32) {
    int i = i_first + t;
    float src = i * SC;
    float fi = floorf(src);
    int i0 = (int)fi;
    float tt = src - fi;
    whv[t] = make_float4(cub_gt1(1.0f + tt), cub_le1(tt), cub_le1(1.0f - tt), cub_gt1(2.0f - tt));
    hrr[t] = make_int4(min(max(i0 - 1, 0), HIN - 1) - hmin, min(max(i0, 0), HIN - 1) - hmin,
                       min(max(i0 + 1, 0), HIN - 1) - hmin, min(max(i0 + 2, 0), HIN - 1) - hmin);
  }
  // load needed z rows
  const float* zb = z + ((size_t)b * COUT + o) * (HIN * WIN);
  for (int q = t; q < nh * 32; q += 256) {
    int hr = q >> 5, w4 = q & 31;
    *reinterpret_cast<float4*>(&zrow[hr][w4 * 4]) =
        *reinterpret_cast<const float4*>(zb + (size_t)(hmin + hr) * WIN + w4 * 4);
  }
  __syncthreads();

  // horizontal pass: trow[hr][j]
  {
    int j = t;
    float4 wv = wwj[j];
    int4 ji = jidx[j];
    for (int hr = 0; hr < nh; ++hr) {
      float v = wv.x * zrow[hr][ji.x] + wv.y * zrow[hr][ji.y] +
                wv.z * zrow[hr][ji.z] + wv.w * zrow[hr][ji.w];
      trow[hr][j] = v;
    }
  }
  __syncthreads();

  // vertical pass + bias + LeakyReLU, float4 stores
  const float bv = bias[o];
  const int j4 = t & 63;
  const int iw = t >> 6;
  float* ob = out + ((size_t)b * COUT + o) * (HOUT * WOUT);
  for (int ii = iw; ii < 32; ii += 4) {
    int i = i_first + ii;
    float4 wv = whv[ii];
    int4 hr = hrr[ii];
    float4 t0 = *reinterpret_cast<const float4*>(&trow[hr.x][j4 * 4]);
    float4 t1 = *reinterpret_cast<const float4*>(&trow[hr.y][j4 * 4]);
    float4 t2 = *reinterpret_cast<const float4*>(&trow[hr.z][j4 * 4]);
    float4 t3 = *reinterpret_cast<const float4*>(&trow[hr.w][j4 * 4]);
    float4 r;
    r.x = wv.x * t0.x + wv.y * t1.x + wv.z * t2.x + wv.w * t3.x + bv;
    r.y = wv.x * t0.y + wv.y * t1.y + wv.z * t2.y + wv.w * t3.y + bv;
    r.z = wv.x * t0.z + wv.y * t1.z + wv.z * t2.z + wv.w * t3.z + bv;
    r.w = wv.x * t0.w + wv.y * t1.w + wv.z * t2.w + wv.w * t3.w + bv;
    r.x = r.x >= 0.f ? r.x : r.x * NEG;
    r.y = r.y >= 0.f ? r.y : r.y * NEG;
    r.z = r.z >= 0.f ? r.z : r.z * NEG;
    r.w = r.w >= 0.f ? r.w : r.w * NEG;
    *reinterpret_cast<float4*>(ob + (size_t)i * WOUT + j4 * 4) = r;
  }
}

extern "C" void kernel_launch(void* const* d_in, const int* in_sizes, int n_in,
                              void* d_out, int out_size, void* d_ws, size_t ws_size,
                              hipStream_t stream) {
  const float* x = (const float*)d_in[0];
  const float* wgt = (const float*)d_in[1];
  const float* bias = (const float*)d_in[2];
  float* out = (float*)d_out;

  // workspace layout: [0, 64MB) z fp32 ; [64MB, +64KB) W bf16
  float* z = (float*)d_ws;
  short* wbf = (short*)((char*)d_ws + (size_t)BB * COUT * HIN * WIN * sizeof(float));

  wconv_kernel<<<dim3(COUT * CIN / (256 * 4)), 256, 0, stream>>>(wgt, wbf);
  conv1x1_kernel<<<dim3(HIN, BB), 256, 0, stream>>>(x, wbf, z);
  upsample_kernel<<<dim3((COUT) * 8, BB), 256, 0, stream>>>(z, bias, out);
}

// Round 2
// 122.687 us; speedup vs baseline: 1.0242x; 1.0242x over previous
//
#include <hip/hip_runtime.h>
#include <hip/hip_bf16.h>

#define BB 8
#define CIN 256
#define COUT 128
#define HIN 128
#define WIN 128
#define HOUT 256
#define WOUT 256

typedef __attribute__((ext_vector_type(8))) short bf16x8;
typedef __attribute__((ext_vector_type(4))) float f32x4;

__device__ __forceinline__ short f2bf(float f) {
  __hip_bfloat16 h = __float2bfloat16(f);  // RNE
  return *reinterpret_cast<short*>(&h);
}
__device__ __forceinline__ float bf2f(short s) {
  unsigned int u = ((unsigned int)(unsigned short)s) << 16;
  return __uint_as_float(u);
}

// ---------------- Kernel 0: W fp32 -> bf16 (row-major [COUT][CIN]) --------
__global__ __launch_bounds__(256) void wconv_kernel(const float* __restrict__ wgt,
                                                    short* __restrict__ wbf) {
  int idx = (blockIdx.x * 256 + threadIdx.x) * 4;
  float4 f = *reinterpret_cast<const float4*>(wgt + idx);
  short4 pk = make_short4(f2bf(f.x), f2bf(f.y), f2bf(f.z), f2bf(f.w));
  *reinterpret_cast<short4*>(wbf + idx) = pk;
}

// ---------------- Kernel 1: z[b][o][h][w] = sum_c W[o][c] x[b][c][h][w] ----
// grid (128 h, 8 b), 256 threads (4 waves, 2x2 wave tile).
// Swapped MFMA: A = x-tile (rows = w), B = W (cols = o) so each lane's 4
// accumulator rows are 4 consecutive w -> packed short4 bf16 z-store.
__global__ __launch_bounds__(256) void conv1x1_kernel(const float* __restrict__ x,
                                                      const short* __restrict__ wbf,
                                                      short* __restrict__ zbf) {
  __shared__ __align__(16) short xs[128][264];  // [w][c] bf16, +8 pad
  const int h = blockIdx.x, b = blockIdx.y;
  const int t = threadIdx.x;

  {
    const float* xb = x + (size_t)b * (CIN * HIN * WIN) + (size_t)h * WIN;
    int w0 = t & 127;
    int ch = t >> 7;
#pragma unroll
    for (int cc = 0; cc < 32; ++cc) {
      int c = ch * 128 + cc * 4;
      float f0 = xb[(size_t)(c + 0) * (HIN * WIN) + w0];
      float f1 = xb[(size_t)(c + 1) * (HIN * WIN) + w0];
      float f2 = xb[(size_t)(c + 2) * (HIN * WIN) + w0];
      float f3 = xb[(size_t)(c + 3) * (HIN * WIN) + w0];
      short4 pk = make_short4(f2bf(f0), f2bf(f1), f2bf(f2), f2bf(f3));
      *reinterpret_cast<short4*>(&xs[w0][c]) = pk;
    }
  }
  __syncthreads();

  const int lane = t & 63, wid = t >> 6;
  const int wm = wid >> 1, wn = wid & 1;  // wm: w-half, wn: o-half
  const int r = lane & 15, g = lane >> 4;

  f32x4 acc[4][4];
#pragma unroll
  for (int i = 0; i < 4; ++i)
#pragma unroll
    for (int j = 0; j < 4; ++j)
      acc[i][j] = (f32x4){0.f, 0.f, 0.f, 0.f};

#pragma unroll
  for (int ks = 0; ks < 8; ++ks) {
    int cb = ks * 32 + g * 8;
    bf16x8 xfr[4], wfr[4];
#pragma unroll
    for (int mt = 0; mt < 4; ++mt) {
      int p = wm * 64 + mt * 16 + r;
      xfr[mt] = *reinterpret_cast<const bf16x8*>(&xs[p][cb]);
    }
#pragma unroll
    for (int nt = 0; nt < 4; ++nt) {
      int o = wn * 64 + nt * 16 + r;
      wfr[nt] = *reinterpret_cast<const bf16x8*>(wbf + (size_t)o * CIN + cb);
    }
#pragma unroll
    for (int mt = 0; mt < 4; ++mt)
#pragma unroll
      for (int nt = 0; nt < 4; ++nt)
        acc[mt][nt] = __builtin_amdgcn_mfma_f32_16x16x32_bf16(xfr[mt], wfr[nt], acc[mt][nt], 0, 0, 0);
  }

  // D layout: row = g*4+q -> w, col = r -> o. Pack 4 consecutive w as bf16x4.
  short* zb = zbf + (size_t)b * (COUT * HIN * WIN) + (size_t)h * WIN;
#pragma unroll
  for (int mt = 0; mt < 4; ++mt) {
#pragma unroll
    for (int nt = 0; nt < 4; ++nt) {
      int w4 = wm * 64 + mt * 16 + g * 4;
      int o = wn * 64 + nt * 16 + r;
      short4 pk = make_short4(f2bf(acc[mt][nt][0]), f2bf(acc[mt][nt][1]),
                              f2bf(acc[mt][nt][2]), f2bf(acc[mt][nt][3]));
      *reinterpret_cast<short4*>(zb + (size_t)o * (HIN * WIN) + w4) = pk;
    }
  }
}

// ---------------- Kernel 2: separable bicubic 2x + bias + LeakyReLU -------
#define ACF (-0.75f)
#define NEG 0.01f

__device__ __forceinline__ float cub_le1(float s) {  // 0 <= s <= 1
  return ((ACF + 2.0f) * s - (ACF + 3.0f)) * s * s + 1.0f;
}
__device__ __forceinline__ float cub_gt1(float s) {  // 1 <= s <= 2 (0 at 1,2)
  return (((s - 5.0f) * s + 8.0f) * s - 4.0f) * ACF;
}
__device__ __forceinline__ float4 mkw(float tt) {
  return make_float4(cub_gt1(1.0f + tt), cub_le1(tt), cub_le1(1.0f - tt), cub_gt1(2.0f - tt));
}

// Exact 2x geometry (scale = 127/255):
//   out 2u   : i0 = u-1, t = (255-u)/255, taps u-2..u+1   (u=0 degenerates to copy)
//   out 2u+1 : i0 = u,   t = (127-u)/255, taps u-1..u+2
// So an output pair shares a clamped 5-tap window u-2..u+2.
// grid.x = 1024 (o = bx>>3, itile = bx&7), grid.y = b; 256 threads
__global__ __launch_bounds__(256) void upsample_kernel(const short* __restrict__ zbf,
                                                       const float* __restrict__ bias,
                                                       float* __restrict__ out) {
  __shared__ float zrow[20][128];
  __shared__ float trow[20][256];

  const int bx = blockIdx.x;
  const int itile = bx & 7;
  const int o = bx >> 3;
  const int b = blockIdx.y;
  const int t = threadIdx.x;

  // h-range for this 32-row output tile (pair indices m = itile*16 .. +15)
  const int m0 = itile * 16;
  const int hmin = max(m0 - 2, 0);
  const int hmax = min(m0 + 15 + 2, HIN - 1);
  const int nh = hmax - hmin + 1;  // <= 20

  // stage z rows (bf16 -> f32)
  {
    const short* zb = zbf + ((size_t)b * COUT + o) * (HIN * WIN);
    for (int q = t; q < nh * 16; q += 256) {
      int hr = q >> 4, c8 = (q & 15) * 8;
      bf16x8 v = *reinterpret_cast<const bf16x8*>(zb + (size_t)(hmin + hr) * WIN + c8);
      float4 lo = make_float4(bf2f(v[0]), bf2f(v[1]), bf2f(v[2]), bf2f(v[3]));
      float4 hi = make_float4(bf2f(v[4]), bf2f(v[5]), bf2f(v[6]), bf2f(v[7]));
      *reinterpret_cast<float4*>(&zrow[hr][c8]) = lo;
      *reinterpret_cast<float4*>(&zrow[hr][c8 + 4]) = hi;
    }
  }
  __syncthreads();

  // horizontal pass: thread u makes cols (2u, 2u+1) from 5-tap window
  {
    const int u = t & 127;
    const int pr = t >> 7;
    const float uf = (float)u;
    const float4 wA = mkw((255.0f - uf) * (1.0f / 255.0f));
    const float4 wB = mkw((127.0f - uf) * (1.0f / 255.0f));
    const int i0c = max(u - 2, 0);
    const int i1c = max(u - 1, 0);
    const int i2c = u;
    const int i3c = min(u + 1, WIN - 1);
    const int i4c = min(u + 2, WIN - 1);
    for (int hr = pr; hr < nh; hr += 2) {
      float z0 = zrow[hr][i0c], z1 = zrow[hr][i1c], z2 = zrow[hr][i2c];
      float z3 = zrow[hr][i3c], z4 = zrow[hr][i4c];
      float oa = wA.x * z0 + wA.y * z1 + wA.z * z2 + wA.w * z3;
      float ob = wB.x * z1 + wB.y * z2 + wB.z * z3 + wB.w * z4;
      *reinterpret_cast<float2*>(&trow[hr][u * 2]) = make_float2(oa, ob);
    }
  }
  __syncthreads();

  // vertical pass: row pair (2m, 2m+1) from 5 trow rows; + bias + LeakyReLU
  const float bv = bias[o];
  const int j4 = t & 63;
  const int iw = t >> 6;
  float* obase = out + ((size_t)b * COUT + o) * (HOUT * WOUT);
  for (int mm = iw; mm < 16; mm += 4) {
    int m = m0 + mm;
    float mf = (float)m;
    float4 wA = mkw((255.0f - mf) * (1.0f / 255.0f));
    float4 wB = mkw((127.0f - mf) * (1.0f / 255.0f));
    int r0 = max(m - 2, 0) - hmin;
    int r1 = max(m - 1, 0) - hmin;
    int r2 = m - hmin;
    int r3 = min(m + 1, HIN - 1) - hmin;
    int r4 = min(m + 2, HIN - 1) - hmin;
    float4 t0 = *reinterpret_cast<const float4*>(&trow[r0][j4 * 4]);
    float4 t1 = *reinterpret_cast<const float4*>(&trow[r1][j4 * 4]);
    float4 t2 = *reinterpret_cast<const float4*>(&trow[r2][j4 * 4]);
    float4 t3 = *reinterpret_cast<const float4*>(&trow[r3][j4 * 4]);
    float4 t4 = *reinterpret_cast<const float4*>(&trow[r4][j4 * 4]);
    float4 rA, rB;
    rA.x = wA.x * t0.x + wA.y * t1.x + wA.z * t2.x + wA.w * t3.x + bv;
    rA.y = wA.x * t0.y + wA.y * t1.y + wA.z * t2.y + wA.w * t3.y + bv;
    rA.z = wA.x * t0.z + wA.y * t1.z + wA.z * t2.z + wA.w * t3.z + bv;
    rA.w = wA.x * t0.w + wA.y * t1.w + wA.z * t2.w + wA.w * t3.w + bv;
    rB.x = wB.x * t1.x + wB.y * t2.x + wB.z * t3.x + wB.w * t4.x + bv;
    rB.y = wB.x * t1.y + wB.y * t2.y + wB.z * t3.y + wB.w * t4.y + bv;
    rB.z = wB.x * t1.z + wB.y * t2.z + wB.z * t3.z + wB.w * t4.z + bv;
    rB.w = wB.x * t1.w + wB.y * t2.w + wB.z * t3.w + wB.w * t4.w + bv;
    rA.x = rA.x >= 0.f ? rA.x : rA.x * NEG;
    rA.y = rA.y >= 0.f ? rA.y : rA.y * NEG;
    rA.z = rA.z >= 0.f ? rA.z : rA.z * NEG;
    rA.w = rA.w >= 0.f ? rA.w : rA.w * NEG;
    rB.x = rB.x >= 0.f ? rB.x : rB.x * NEG;
    rB.y = rB.y >= 0.f ? rB.y : rB.y * NEG;
    rB.z = rB.z >= 0.f ? rB.z : rB.z * NEG;
    rB.w = rB.w >= 0.f ? rB.w : rB.w * NEG;
    int iA = itile * 32 + 2 * mm;
    *reinterpret_cast<float4*>(obase + (size_t)iA * WOUT + j4 * 4) = rA;
    *reinterpret_cast<float4*>(obase + (size_t)(iA + 1) * WOUT + j4 * 4) = rB;
  }
}

extern "C" void kernel_launch(void* const* d_in, const int* in_sizes, int n_in,
                              void* d_out, int out_size, void* d_ws, size_t ws_size,
                              hipStream_t stream) {
  const float* x = (const float*)d_in[0];
  const float* wgt = (const float*)d_in[1];
  const float* bias = (const float*)d_in[2];
  float* out = (float*)d_out;

  // workspace: [0, 32MB) z bf16 ; then W bf16 (64KB)
  short* zbf = (short*)d_ws;
  short* wbf = (short*)((char*)d_ws + (size_t)BB * COUT * HIN * WIN * sizeof(short));

  wconv_kernel<<<dim3(COUT * CIN / (256 * 4)), 256, 0, stream>>>(wgt, wbf);
  conv1x1_kernel<<<dim3(HIN, BB), 256, 0, stream>>>(x, wbf, zbf);
  upsample_kernel<<<dim3(COUT * 8, BB), 256, 0, stream>>>(zbf, bias, out);
}